// Round 1
// baseline (169.663 us; speedup 1.0000x reference)
//
#include <hip/hip_runtime.h>
#include <math.h>

#define BB 64
#define HH 512
#define WW 512
#define HWQ (HH*WW)
#define NTOT ((size_t)BB*HWQ)
#define PR 15

// ws layout:
//   [0, NTOT) bytes            : vertical box sums as uint8 (exact ints 0..31)
//   [NTOT, ...)                : doubles:
//     [0..63]    bl partial slots
//     [64..127]  sl partial slots
//     [128+3b+0] TP_b, +1 sumP_b, +2 sumT_b
#define ACC_DOUBLES (128 + 3*BB)

__global__ void k_zero(double* __restrict__ acc) {
  int t = threadIdx.x;
  if (t < ACC_DOUBLES) acc[t] = 0.0;
}

// vertical 31-tap box sum of binary target -> uint8
__global__ __launch_bounds__(256) void k_vsum(const float* __restrict__ tgt,
                                              unsigned char* __restrict__ vs) {
  int gid = blockIdx.x * 256 + threadIdx.x;     // 65536 threads
  int x   = (gid & 127) * 4;                    // 128 float4 column groups
  int seg = (gid >> 7) & 7;                     // 8 row segments of 64
  int b   = gid >> 10;
  const float* timg = tgt + (size_t)b * HWQ;
  unsigned char* vimg = vs + (size_t)b * HWQ;
  int y0 = seg * 64;
  float4 s = make_float4(0.f, 0.f, 0.f, 0.f);
  for (int r = y0 - PR; r <= y0 + PR; ++r) {
    if (r >= 0 && r < HH) {
      const float4 t = *(const float4*)(timg + (size_t)r * WW + x);
      s.x += t.x; s.y += t.y; s.z += t.z; s.w += t.w;
    }
  }
  for (int y = y0; y < y0 + 64; ++y) {
    uchar4 o;
    o.x = (unsigned char)(s.x + 0.5f);
    o.y = (unsigned char)(s.y + 0.5f);
    o.z = (unsigned char)(s.z + 0.5f);
    o.w = (unsigned char)(s.w + 0.5f);
    *(uchar4*)(vimg + (size_t)y * WW + x) = o;
    int ra = y + PR + 1, rs = y - PR;
    if (ra < HH) {
      const float4 t = *(const float4*)(timg + (size_t)ra * WW + x);
      s.x += t.x; s.y += t.y; s.z += t.z; s.w += t.w;
    }
    if (rs >= 0) {
      const float4 t = *(const float4*)(timg + (size_t)rs * WW + x);
      s.x -= t.x; s.y -= t.y; s.z -= t.z; s.w -= t.w;
    }
  }
}

__device__ inline float wredf(float v) {
#pragma unroll
  for (int o = 32; o > 0; o >>= 1) v += __shfl_down(v, o, 64);
  return v;
}

// main fused kernel: block = one image b, 4 rows; wave w -> row y0+w; lane -> 8 cols
__global__ __launch_bounds__(256) void k_main(const float* __restrict__ pred,
                                              const float* __restrict__ tgt,
                                              const unsigned char* __restrict__ vs,
                                              double* __restrict__ acc) {
  __shared__ float s_vs[4][544];   // 512 + 16 pad each side
  __shared__ float s_tg[6][516];   // 514 used (x: -1..512), stride 516 for 16B align
  __shared__ float s_red[4][5];

  int blk = blockIdx.x;            // 64*128
  int b   = blk >> 7;
  int y0  = (blk & 127) * 4;
  int tid = threadIdx.x;
  int wv = tid >> 6, lane = tid & 63;

  const float* timg = tgt + (size_t)b * HWQ;
  const unsigned char* vimg = vs + (size_t)b * HWQ;

  // stage vsum rows (u8 -> f32), vectorized uchar4
  for (int i = tid; i < 4 * (WW / 4); i += 256) {      // 512 iters
    int r = i >> 7, c4 = (i & 127) * 4;
    uchar4 u = *(const uchar4*)(vimg + (size_t)(y0 + r) * WW + c4);
    s_vs[r][16 + c4 + 0] = (float)u.x;
    s_vs[r][16 + c4 + 1] = (float)u.y;
    s_vs[r][16 + c4 + 2] = (float)u.z;
    s_vs[r][16 + c4 + 3] = (float)u.w;
  }
  if (tid < 128) {                 // zero pads
    int r = tid >> 5, c = tid & 31;
    s_vs[r][c < 16 ? c : 512 + c] = 0.f;   // left 0..15, right 528..543
  }
  // stage target rows y0-1 .. y0+4 with 1-col zero pad
  for (int i = tid; i < 6 * 514; i += 256) {
    int r = i / 514, c = i - r * 514;
    int gy = y0 - 1 + r, gx = c - 1;
    float v = 0.f;
    if (gy >= 0 && gy < HH && gx >= 0 && gx < WW) v = timg[(size_t)gy * WW + gx];
    s_tg[r][c] = v;
  }
  __syncthreads();

  int y = y0 + wv;
  int x0 = lane * 8;

  const float* prow = pred + (size_t)b * HWQ + (size_t)y * WW + x0;
  float4 pA = *(const float4*)prow;
  float4 pB = *(const float4*)(prow + 4);
  float pv[8] = {pA.x, pA.y, pA.z, pA.w, pB.x, pB.y, pB.z, pB.w};

  // vsum band: padded idx [x0 .. x0+39]
  float vband[40];
  {
    const float4* vp = (const float4*)&s_vs[wv][x0];
#pragma unroll
    for (int j = 0; j < 10; ++j) {
      float4 t = vp[j];
      vband[4*j] = t.x; vband[4*j+1] = t.y; vband[4*j+2] = t.z; vband[4*j+3] = t.w;
    }
  }
  // target rows, padded idx [x0 .. x0+11] (need x0..x0+9)
  float tm[12], t0r[12], tp[12];
  {
    const float4* aq = (const float4*)&s_tg[wv][x0];
    const float4* bq = (const float4*)&s_tg[wv + 1][x0];
    const float4* cq = (const float4*)&s_tg[wv + 2][x0];
#pragma unroll
    for (int j = 0; j < 3; ++j) {
      float4 u = aq[j]; tm[4*j] = u.x; tm[4*j+1] = u.y; tm[4*j+2] = u.z; tm[4*j+3] = u.w;
      float4 v = bq[j]; t0r[4*j] = v.x; t0r[4*j+1] = v.y; t0r[4*j+2] = v.z; t0r[4*j+3] = v.w;
      float4 w = cq[j]; tp[4*j] = w.x; tp[4*j+1] = w.y; tp[4*j+2] = w.z; tp[4*j+3] = w.w;
    }
  }

  // horizontal sliding 31-tap: window for col x0+c = vband[c+1 .. c+31] (exact ints)
  float sw = 0.f;
#pragma unroll
  for (int j = 1; j <= 31; ++j) sw += vband[j];

  float a_bl = 0.f, a_sl = 0.f, a_pt = 0.f, a_p = 0.f, a_t = 0.f;
#pragma unroll
  for (int c = 0; c < 8; ++c) {
    float tc = t0r[c + 1];
    float p  = pv[c];
    float bce = -(tc * logf(p) + (1.f - tc) * logf(1.f - p));
    float gxv = (tm[c+2] - tm[c]) + 2.f * (t0r[c+2] - t0r[c]) + (tp[c+2] - tp[c]);
    float gyv = (tp[c] - tm[c]) + 2.f * (tp[c+1] - tm[c+1]) + (tp[c+2] - tm[c+2]);
    float tb  = sqrtf(gxv * gxv + gyv * gyv + 1e-12f);
    float bwt = 1.f + 10.f * tb;
    float pooled = sw * (1.f / 961.f);
    float weit = 1.f + 5.f * fabsf(pooled - tc);
    a_bl += bwt * bce;
    a_sl += weit * bce;
    a_pt += p * tc;
    a_p  += p;
    a_t  += tc;
    sw += vband[c + 32] - vband[c + 1];
  }

  a_bl = wredf(a_bl); a_sl = wredf(a_sl); a_pt = wredf(a_pt);
  a_p = wredf(a_p);   a_t = wredf(a_t);
  if (lane == 0) {
    s_red[wv][0] = a_bl; s_red[wv][1] = a_sl; s_red[wv][2] = a_pt;
    s_red[wv][3] = a_p;  s_red[wv][4] = a_t;
  }
  __syncthreads();
  if (tid == 0) {
    float rbl = 0, rsl = 0, rpt = 0, rp = 0, rt = 0;
    for (int w2 = 0; w2 < 4; ++w2) {
      rbl += s_red[w2][0]; rsl += s_red[w2][1]; rpt += s_red[w2][2];
      rp  += s_red[w2][3]; rt  += s_red[w2][4];
    }
    int slot = blk & 63;
    atomicAdd(&acc[slot],            (double)rbl);
    atomicAdd(&acc[64 + slot],       (double)rsl);
    atomicAdd(&acc[128 + 3*b + 0],   (double)rpt);
    atomicAdd(&acc[128 + 3*b + 1],   (double)rp);
    atomicAdd(&acc[128 + 3*b + 2],   (double)rt);
  }
}

__global__ void k_final(const double* __restrict__ acc, float* __restrict__ out) {
  int t = threadIdx.x;  // 64 threads = 1 wave
  double bl = acc[t], sl = acc[64 + t];
  double TP = acc[128 + 3*t], Ps = acc[128 + 3*t + 1], Ts = acc[128 + 3*t + 2];
  double FP = Ps - TP, FN = Ts - TP;
  double tv = (TP + 1e-6) / (TP + 0.3 * FP + 0.7 * FN + 1e-6);
  double om = 1.0 - tv;
  if (om < 0.0) om = 0.0;
  double term = pow(om, 1.0 / 1.33);
#pragma unroll
  for (int o = 32; o > 0; o >>= 1) {
    bl   += __shfl_down(bl, o, 64);
    sl   += __shfl_down(sl, o, 64);
    term += __shfl_down(term, o, 64);
  }
  if (t == 0) {
    double ftl = term / 64.0;
    double n = (double)NTOT;
    out[0] = (float)(ftl + 0.5 * (bl / n) + 0.3 * (sl / n));
  }
}

extern "C" void kernel_launch(void* const* d_in, const int* in_sizes, int n_in,
                              void* d_out, int out_size, void* d_ws, size_t ws_size,
                              hipStream_t stream) {
  (void)in_sizes; (void)n_in; (void)out_size; (void)ws_size;
  const float* pred = (const float*)d_in[0];
  const float* tgt  = (const float*)d_in[1];
  unsigned char* vsb = (unsigned char*)d_ws;
  double* acc = (double*)((char*)d_ws + NTOT);

  k_zero<<<1, 512, 0, stream>>>(acc);
  k_vsum<<<256, 256, 0, stream>>>(tgt, vsb);
  k_main<<<BB * 128, 256, 0, stream>>>(pred, tgt, vsb, acc);
  k_final<<<1, 64, 0, stream>>>(acc, (float*)d_out);
}

// Round 2
// 133.813 us; speedup vs baseline: 1.2679x; 1.2679x over previous
//
#include <hip/hip_runtime.h>
#include <math.h>

#define BB 64
#define HH 512
#define WW 512
#define HWQ (HH*WW)
#define NTOT ((size_t)BB*HWQ)
#define PR 15

// ws layout:
//   [0, NTOT) bytes : vertical box sums as uint8 (exact ints 0..31)
//   [NTOT, ...)     : doubles: [0..63] bl slots, [64..127] sl slots,
//                     [128+3b+{0,1,2}] = TP_b, sumP_b, sumT_b
#define ACC_DOUBLES (128 + 3*BB)

// XOR swizzle on float4-block index: keeps 16B alignment, kills the
// 16-way conflict from 128B lane stride (lanes l, l+4 same bank quad).
#define BSWZ(B) ((B) ^ (((B) >> 3) & 7))

// vertical 31-tap box sum of binary target -> uint8 (+ acc zeroing in block 0)
__global__ __launch_bounds__(256) void k_vsum(const float* __restrict__ tgt,
                                              unsigned char* __restrict__ vs,
                                              double* __restrict__ acc) {
  if (blockIdx.x == 0) {
    for (int i = threadIdx.x; i < ACC_DOUBLES; i += 256) acc[i] = 0.0;
  }
  int gid = blockIdx.x * 256 + threadIdx.x;     // 131072 threads
  int x   = (gid & 127) * 4;                    // 128 float4 column groups
  int seg = (gid >> 7) & 15;                    // 16 row segments of 32
  int b   = gid >> 11;
  const float* timg = tgt + (size_t)b * HWQ;
  unsigned char* vimg = vs + (size_t)b * HWQ;
  int y0 = seg * 32;
  float4 s = make_float4(0.f, 0.f, 0.f, 0.f);
  int lo = y0 - PR; if (lo < 0) lo = 0;
  int hi = y0 + PR; if (hi > HH - 1) hi = HH - 1;
  for (int r = lo; r <= hi; ++r) {
    const float4 t = *(const float4*)(timg + (size_t)r * WW + x);
    s.x += t.x; s.y += t.y; s.z += t.z; s.w += t.w;
  }
#pragma unroll 4
  for (int y = y0; y < y0 + 32; ++y) {
    uchar4 o;
    o.x = (unsigned char)(s.x + 0.5f);
    o.y = (unsigned char)(s.y + 0.5f);
    o.z = (unsigned char)(s.z + 0.5f);
    o.w = (unsigned char)(s.w + 0.5f);
    *(uchar4*)(vimg + (size_t)y * WW + x) = o;
    int ra = y + PR + 1, rs = y - PR;
    if (ra < HH) {
      const float4 t = *(const float4*)(timg + (size_t)ra * WW + x);
      s.x += t.x; s.y += t.y; s.z += t.z; s.w += t.w;
    }
    if (rs >= 0) {
      const float4 t = *(const float4*)(timg + (size_t)rs * WW + x);
      s.x -= t.x; s.y -= t.y; s.z -= t.z; s.w -= t.w;
    }
  }
}

__device__ inline float wredf(float v) {
#pragma unroll
  for (int o = 32; o > 0; o >>= 1) v += __shfl_down(v, o, 64);
  return v;
}

// main fused kernel: block = one image b, 4 rows; wave w -> row y0+w; lane -> 8 cols
__global__ __launch_bounds__(256) void k_main(const float* __restrict__ pred,
                                              const float* __restrict__ tgt,
                                              const unsigned char* __restrict__ vs,
                                              double* __restrict__ acc) {
  // s_vs: per-row 544 floats (16 pad | 512 | 16 pad) = 136 blocks, XOR-swizzled
  // s_tg: per-row slots 0..519 (slot s <-> global col s-4) = 130 blocks (pad to 136)
  __shared__ float s_vs[4][544];
  __shared__ float s_tg[6][544];
  __shared__ float s_red[4][5];

  int blk = blockIdx.x;            // 64*128
  int b   = blk >> 7;
  int y0  = (blk & 127) * 4;
  int tid = threadIdx.x;
  int wv = tid >> 6, lane = tid & 63;

  const float* timg = tgt + (size_t)b * HWQ;
  const unsigned char* vimg = vs + (size_t)b * HWQ;

  // hoist pred loads: overlap global latency with staging
  int y = y0 + wv;
  int x0 = lane * 8;
  const float* prow = pred + (size_t)b * HWQ + (size_t)y * WW + x0;
  float4 pA = *(const float4*)prow;
  float4 pB = *(const float4*)(prow + 4);

  // stage vsum rows (u8 -> f32), float4 stores to swizzled blocks
#pragma unroll
  for (int ii = 0; ii < 2; ++ii) {
    int i = tid + 256 * ii;        // 512 = 4 rows x 128 uchar4
    int r = i >> 7, c4 = (i & 127) * 4;
    uchar4 u = *(const uchar4*)(vimg + (size_t)(y0 + r) * WW + c4);
    int B = 4 + (i & 127);         // padded slot (16+c4)/4
    float4 f = make_float4((float)u.x, (float)u.y, (float)u.z, (float)u.w);
    *(float4*)&s_vs[r][4 * BSWZ(B)] = f;
  }
  if (tid < 32) {                  // zero pad blocks 0..3 and 132..135
    int r = tid >> 3, q = tid & 7;
    int B = (q < 4) ? q : (128 + q);
    *(float4*)&s_vs[r][4 * BSWZ(B)] = make_float4(0.f, 0.f, 0.f, 0.f);
  }
  // stage target rows y0-1 .. y0+4; slot s <-> global col s-4
#pragma unroll
  for (int ii = 0; ii < 3; ++ii) {
    int i = tid + 256 * ii;        // 768 = 6 rows x 128 float4
    int r = i >> 7, k = i & 127;
    int gy = y0 - 1 + r;
    float4 v = make_float4(0.f, 0.f, 0.f, 0.f);
    if (gy >= 0 && gy < HH) v = *(const float4*)(timg + (size_t)gy * WW + 4 * k);
    *(float4*)&s_tg[r][4 * BSWZ(k + 1)] = v;
  }
  if (tid < 12) {                  // zero blocks 0 (slots 0..3) and 129 (516..519)
    int r = tid >> 1;
    int B = (tid & 1) ? 129 : 0;
    *(float4*)&s_tg[r][4 * BSWZ(B)] = make_float4(0.f, 0.f, 0.f, 0.f);
  }
  __syncthreads();

  float pv[8] = {pA.x, pA.y, pA.z, pA.w, pB.x, pB.y, pB.z, pB.w};

  // vsum band: padded slots [x0 .. x0+39] = blocks 2l .. 2l+9
  float vband[40];
  {
    const float* row = s_vs[wv];
#pragma unroll
    for (int j = 0; j < 10; ++j) {
      int Bp = BSWZ(2 * lane + j);
      const float4 t = *(const float4*)&row[4 * Bp];
      vband[4*j] = t.x; vband[4*j+1] = t.y; vband[4*j+2] = t.z; vband[4*j+3] = t.w;
    }
  }
  // target rows: slots [8l .. 8l+15] (use 3..12); tm/t0r/tp idx k <-> global col 8l+k-4
  float tm[16], t0r[16], tp[16];
#pragma unroll
  for (int j = 0; j < 4; ++j) {
    int Bp = BSWZ(2 * lane + j);
    float4 u = *(const float4*)&s_tg[wv][4 * Bp];
    float4 v = *(const float4*)&s_tg[wv + 1][4 * Bp];
    float4 w = *(const float4*)&s_tg[wv + 2][4 * Bp];
    tm[4*j] = u.x; tm[4*j+1] = u.y; tm[4*j+2] = u.z; tm[4*j+3] = u.w;
    t0r[4*j] = v.x; t0r[4*j+1] = v.y; t0r[4*j+2] = v.z; t0r[4*j+3] = v.w;
    tp[4*j] = w.x; tp[4*j+1] = w.y; tp[4*j+2] = w.z; tp[4*j+3] = w.w;
  }

  // horizontal sliding 31-tap: window for col x0+c = vband[c+1 .. c+31] (exact ints)
  float sw = 0.f;
#pragma unroll
  for (int j = 1; j <= 31; ++j) sw += vband[j];

  float a_bl = 0.f, a_sl = 0.f, a_pt = 0.f, a_p = 0.f, a_t = 0.f;
#pragma unroll
  for (int c = 0; c < 8; ++c) {
    float tc = t0r[c + 4];
    float p  = pv[c];
    float bce = -(tc * logf(p) + (1.f - tc) * logf(1.f - p));
    float gxv = (tm[c+5] - tm[c+3]) + 2.f * (t0r[c+5] - t0r[c+3]) + (tp[c+5] - tp[c+3]);
    float gyv = (tp[c+3] - tm[c+3]) + 2.f * (tp[c+4] - tm[c+4]) + (tp[c+5] - tm[c+5]);
    float tb  = sqrtf(gxv * gxv + gyv * gyv + 1e-12f);
    float bwt = 1.f + 10.f * tb;
    float pooled = sw * (1.f / 961.f);
    float weit = 1.f + 5.f * fabsf(pooled - tc);
    a_bl += bwt * bce;
    a_sl += weit * bce;
    a_pt += p * tc;
    a_p  += p;
    a_t  += tc;
    sw += vband[c + 32] - vband[c + 1];
  }

  a_bl = wredf(a_bl); a_sl = wredf(a_sl); a_pt = wredf(a_pt);
  a_p = wredf(a_p);   a_t = wredf(a_t);
  if (lane == 0) {
    s_red[wv][0] = a_bl; s_red[wv][1] = a_sl; s_red[wv][2] = a_pt;
    s_red[wv][3] = a_p;  s_red[wv][4] = a_t;
  }
  __syncthreads();
  if (tid == 0) {
    float rbl = 0, rsl = 0, rpt = 0, rp = 0, rt = 0;
    for (int w2 = 0; w2 < 4; ++w2) {
      rbl += s_red[w2][0]; rsl += s_red[w2][1]; rpt += s_red[w2][2];
      rp  += s_red[w2][3]; rt  += s_red[w2][4];
    }
    int slot = blk & 63;
    atomicAdd(&acc[slot],            (double)rbl);
    atomicAdd(&acc[64 + slot],       (double)rsl);
    atomicAdd(&acc[128 + 3*b + 0],   (double)rpt);
    atomicAdd(&acc[128 + 3*b + 1],   (double)rp);
    atomicAdd(&acc[128 + 3*b + 2],   (double)rt);
  }
}

__global__ void k_final(const double* __restrict__ acc, float* __restrict__ out) {
  int t = threadIdx.x;  // 64 threads = 1 wave
  double bl = acc[t], sl = acc[64 + t];
  double TP = acc[128 + 3*t], Ps = acc[128 + 3*t + 1], Ts = acc[128 + 3*t + 2];
  double FP = Ps - TP, FN = Ts - TP;
  double tv = (TP + 1e-6) / (TP + 0.3 * FP + 0.7 * FN + 1e-6);
  double om = 1.0 - tv;
  if (om < 0.0) om = 0.0;
  double term = pow(om, 1.0 / 1.33);
#pragma unroll
  for (int o = 32; o > 0; o >>= 1) {
    bl   += __shfl_down(bl, o, 64);
    sl   += __shfl_down(sl, o, 64);
    term += __shfl_down(term, o, 64);
  }
  if (t == 0) {
    double ftl = term / 64.0;
    double n = (double)NTOT;
    out[0] = (float)(ftl + 0.5 * (bl / n) + 0.3 * (sl / n));
  }
}

extern "C" void kernel_launch(void* const* d_in, const int* in_sizes, int n_in,
                              void* d_out, int out_size, void* d_ws, size_t ws_size,
                              hipStream_t stream) {
  (void)in_sizes; (void)n_in; (void)out_size; (void)ws_size;
  const float* pred = (const float*)d_in[0];
  const float* tgt  = (const float*)d_in[1];
  unsigned char* vsb = (unsigned char*)d_ws;
  double* acc = (double*)((char*)d_ws + NTOT);

  k_vsum<<<512, 256, 0, stream>>>(tgt, vsb, acc);
  k_main<<<BB * 128, 256, 0, stream>>>(pred, tgt, vsb, acc);
  k_final<<<1, 64, 0, stream>>>(acc, (float*)d_out);
}

// Round 4
// 123.260 us; speedup vs baseline: 1.3765x; 1.0856x over previous
//
#include <hip/hip_runtime.h>
#include <math.h>

#define BB 64
#define HH 512
#define WW 512
#define HWQ (HH*WW)
#define NTOT ((size_t)BB*HWQ)
#define PR 15

// ws layout:
//   [0, NTOT) bytes : vertical box sums as uint8 (exact ints 0..31)
//   [NTOT, ...)     : doubles: [0..63] combined-bce slots,
//                     [64+3b+{0,1,2}] = TP_b, sumP_b, sumT_b
#define ACC_DOUBLES (64 + 3*BB)

// vertical 31-tap box sum of binary target -> uint8 (+ acc zeroing in block 0)
__global__ __launch_bounds__(256) void k_vsum(const float* __restrict__ tgt,
                                              unsigned char* __restrict__ vs,
                                              double* __restrict__ acc) {
  if (blockIdx.x == 0) {
    for (int i = threadIdx.x; i < ACC_DOUBLES; i += 256) acc[i] = 0.0;
  }
  int gid = blockIdx.x * 256 + threadIdx.x;     // 131072 threads
  int x   = (gid & 127) * 4;                    // 128 float4 column groups
  int seg = (gid >> 7) & 15;                    // 16 row segments of 32
  int b   = gid >> 11;
  const float* timg = tgt + (size_t)b * HWQ;
  unsigned char* vimg = vs + (size_t)b * HWQ;
  int y0 = seg * 32;
  float4 s = make_float4(0.f, 0.f, 0.f, 0.f);
  int lo = y0 - PR; if (lo < 0) lo = 0;
  int hi = y0 + PR; if (hi > HH - 1) hi = HH - 1;
  for (int r = lo; r <= hi; ++r) {
    const float4 t = *(const float4*)(timg + (size_t)r * WW + x);
    s.x += t.x; s.y += t.y; s.z += t.z; s.w += t.w;
  }
#pragma unroll 4
  for (int y = y0; y < y0 + 32; ++y) {
    uchar4 o;
    o.x = (unsigned char)(s.x + 0.5f);
    o.y = (unsigned char)(s.y + 0.5f);
    o.z = (unsigned char)(s.z + 0.5f);
    o.w = (unsigned char)(s.w + 0.5f);
    *(uchar4*)(vimg + (size_t)y * WW + x) = o;
    int ra = y + PR + 1, rs = y - PR;
    if (ra < HH) {
      const float4 t = *(const float4*)(timg + (size_t)ra * WW + x);
      s.x += t.x; s.y += t.y; s.z += t.z; s.w += t.w;
    }
    if (rs >= 0) {
      const float4 t = *(const float4*)(timg + (size_t)rs * WW + x);
      s.x -= t.x; s.y -= t.y; s.z -= t.z; s.w -= t.w;
    }
  }
}

__device__ inline float wredf(float v) {
#pragma unroll
  for (int o = 32; o > 0; o >>= 1) v += __shfl_down(v, o, 64);
  return v;
}

__device__ inline int bext(unsigned w, int sh) { return (int)((w >> sh) & 0xffu); }
// byte i of the 48B window (col x0-16+i), i compile-time constant after unroll
__device__ inline int bget(const uint4& va, const uint4& vb, const uint4& vc, int i) {
  unsigned w;
  if (i < 16)      w = (i < 4) ? va.x : (i < 8) ? va.y : (i < 12) ? va.z : va.w;
  else if (i < 32) { int j = i - 16; w = (j < 4) ? vb.x : (j < 8) ? vb.y : (j < 12) ? vb.z : vb.w; }
  else             { int j = i - 32; w = (j < 4) ? vc.x : (j < 8) ? vc.y : (j < 12) ? vc.z : vc.w; }
  return bext(w, (i & 3) * 8);
}

// main fused kernel: block = one image b, 4 rows; wave w -> row y0+w; lane -> 8 cols
// No LDS staging: per-lane windows straight from global (L1/L2 absorb the 3x overlap).
__global__ __launch_bounds__(256) void k_main(const float* __restrict__ pred,
                                              const float* __restrict__ tgt,
                                              const unsigned char* __restrict__ vs,
                                              double* __restrict__ acc) {
  __shared__ float s_red[4][4];

  int blk = blockIdx.x;            // 64*128
  int b   = blk >> 7;
  int y0  = (blk & 127) * 4;
  int tid = threadIdx.x;
  int wv = tid >> 6, lane = tid & 63;
  int y  = y0 + wv;
  int x0 = lane * 8;

  const float* pimg = pred + (size_t)b * HWQ;
  const float* timg = tgt  + (size_t)b * HWQ;
  const unsigned char* vimg = vs + (size_t)b * HWQ;

  // pred: 8 cols
  const float* prow = pimg + (size_t)y * WW + x0;
  float4 pA = *(const float4*)prow;
  float4 pB = *(const float4*)(prow + 4);
  float pv[8] = {pA.x, pA.y, pA.z, pA.w, pB.x, pB.y, pB.z, pB.w};

  // vs bytes, cols x0-16 .. x0+31 (zero outside row)
  uint4 va = make_uint4(0,0,0,0), vc = make_uint4(0,0,0,0);
  const unsigned char* vrow = vimg + (size_t)y * WW;
  uint4 vb = *(const uint4*)(vrow + x0);
  if (x0 >= 16)       va = *(const uint4*)(vrow + x0 - 16);
  if (x0 + 31 < WW)   vc = *(const uint4*)(vrow + x0 + 16);
  if (x0 + 8 >= WW) { vb.z = 0u; vb.w = 0u; }   // lane 63: cols 512..519 are pad

  // target rows y-1,y,y+1, cols x0-4 .. x0+11 (zero pad outside image)
  float tr[3][16];
#pragma unroll
  for (int r = 0; r < 3; ++r) {
    int gy = y - 1 + r;
    bool rowok = (gy >= 0) && (gy < HH);
    const float* trow = timg + (size_t)gy * WW;
#pragma unroll
    for (int j = 0; j < 4; ++j) {
      int s = x0 - 4 + 4 * j;
      float4 v = make_float4(0.f, 0.f, 0.f, 0.f);
      if (rowok && s >= 0 && s + 3 < WW) v = *(const float4*)(trow + s);
      tr[r][4*j+0] = v.x; tr[r][4*j+1] = v.y; tr[r][4*j+2] = v.z; tr[r][4*j+3] = v.w;
    }
  }

  // initial 31-window sum for col x0: bytes 1..31
  int sw = 0;
#pragma unroll
  for (int j = 1; j <= 31; ++j) sw += bget(va, vb, vc, j);

  float a_c = 0.f, a_pt = 0.f, a_p = 0.f, a_t = 0.f;
#pragma unroll
  for (int c = 0; c < 8; ++c) {
    float tc = tr[1][c + 4];
    float p  = pv[c];
    float q  = (tc > 0.5f) ? p : 1.f - p;
    float lg = __log2f(q);                       // bce = -ln2 * lg (folded in k_final)
    float gxv = (tr[0][c+5] - tr[0][c+3]) + 2.f*(tr[1][c+5] - tr[1][c+3]) + (tr[2][c+5] - tr[2][c+3]);
    float gyv = (tr[2][c+3] - tr[0][c+3]) + 2.f*(tr[2][c+4] - tr[0][c+4]) + (tr[2][c+5] - tr[0][c+5]);
    float tb  = sqrtf(gxv * gxv + gyv * gyv + 1e-12f);
    float pooled = (float)sw * (1.f / 961.f);
    // 0.5*(1+10tb) + 0.3*(1+5|pooled-t|) = 0.8 + 5 tb + 1.5 |pooled-t|
    float w = 0.8f + 5.f * tb + 1.5f * fabsf(pooled - tc);
    a_c  += w * lg;
    a_pt += p * tc;
    a_p  += p;
    a_t  += tc;
    sw += bget(va, vb, vc, c + 32) - bget(va, vb, vc, c + 1);
  }

  a_c = wredf(a_c); a_pt = wredf(a_pt); a_p = wredf(a_p); a_t = wredf(a_t);
  if (lane == 0) {
    s_red[wv][0] = a_c; s_red[wv][1] = a_pt; s_red[wv][2] = a_p; s_red[wv][3] = a_t;
  }
  __syncthreads();
  if (tid == 0) {
    float rc = 0, rpt = 0, rp = 0, rt = 0;
    for (int w2 = 0; w2 < 4; ++w2) {
      rc += s_red[w2][0]; rpt += s_red[w2][1]; rp += s_red[w2][2]; rt += s_red[w2][3];
    }
    atomicAdd(&acc[blk & 63],       (double)rc);
    atomicAdd(&acc[64 + 3*b + 0],   (double)rpt);
    atomicAdd(&acc[64 + 3*b + 1],   (double)rp);
    atomicAdd(&acc[64 + 3*b + 2],   (double)rt);
  }
}

__global__ void k_final(const double* __restrict__ acc, float* __restrict__ out) {
  int t = threadIdx.x;  // 64 threads = 1 wave
  double cs = acc[t];
  double TP = acc[64 + 3*t], Ps = acc[64 + 3*t + 1], Ts = acc[64 + 3*t + 2];
  double FP = Ps - TP, FN = Ts - TP;
  double tv = (TP + 1e-6) / (TP + 0.3 * FP + 0.7 * FN + 1e-6);
  double om = 1.0 - tv;
  if (om < 0.0) om = 0.0;
  double term = pow(om, 1.0 / 1.33);
#pragma unroll
  for (int o = 32; o > 0; o >>= 1) {
    cs   += __shfl_down(cs, o, 64);
    term += __shfl_down(term, o, 64);
  }
  if (t == 0) {
    double ftl = term / 64.0;
    double n = (double)NTOT;
    // combined weighted-BCE sum: bce = -ln2 * log2(q)
    out[0] = (float)(ftl - 0.6931471805599453 * cs / n);
  }
}

extern "C" void kernel_launch(void* const* d_in, const int* in_sizes, int n_in,
                              void* d_out, int out_size, void* d_ws, size_t ws_size,
                              hipStream_t stream) {
  (void)in_sizes; (void)n_in; (void)out_size; (void)ws_size;
  const float* pred = (const float*)d_in[0];
  const float* tgt  = (const float*)d_in[1];
  unsigned char* vsb = (unsigned char*)d_ws;
  double* acc = (double*)((char*)d_ws + NTOT);

  k_vsum<<<512, 256, 0, stream>>>(tgt, vsb, acc);
  k_main<<<BB * 128, 256, 0, stream>>>(pred, tgt, vsb, acc);
  k_final<<<1, 64, 0, stream>>>(acc, (float*)d_out);
}

// Round 5
// 79.406 us; speedup vs baseline: 2.1367x; 1.5523x over previous
//
#include <hip/hip_runtime.h>
#include <math.h>

#define BB 64
#define HH 512
#define WW 512
#define HWQ (HH*WW)
#define NTOT ((size_t)BB*HWQ)
#define PR 15

// ws layout:
//   [0, NTOT) bytes : vertical box sums as uint8 (exact ints 0..31)
//   [NTOT, ...)     : doubles: [0..63] combined-bce slots,
//                     [64+8b+{0,1,2}] = TP_b, sumP_b, sumT_b (64B-padded per image)
#define ACC_DOUBLES (64 + 8*BB)

// vertical 31-tap box sum of binary target -> uint8 (+ acc zeroing in block 0)
__global__ __launch_bounds__(256) void k_vsum(const float* __restrict__ tgt,
                                              unsigned char* __restrict__ vs,
                                              double* __restrict__ acc) {
  if (blockIdx.x == 0) {
    for (int i = threadIdx.x; i < ACC_DOUBLES; i += 256) acc[i] = 0.0;
  }
  int gid = blockIdx.x * 256 + threadIdx.x;     // 131072 threads
  int x   = (gid & 127) * 4;                    // 128 float4 column groups
  int seg = (gid >> 7) & 15;                    // 16 row segments of 32
  int b   = gid >> 11;
  const float* timg = tgt + (size_t)b * HWQ;
  unsigned char* vimg = vs + (size_t)b * HWQ;
  int y0 = seg * 32;
  float4 s = make_float4(0.f, 0.f, 0.f, 0.f);
  int lo = y0 - PR; if (lo < 0) lo = 0;
  int hi = y0 + PR; if (hi > HH - 1) hi = HH - 1;
  for (int r = lo; r <= hi; ++r) {
    const float4 t = *(const float4*)(timg + (size_t)r * WW + x);
    s.x += t.x; s.y += t.y; s.z += t.z; s.w += t.w;
  }
#pragma unroll 4
  for (int y = y0; y < y0 + 32; ++y) {
    uchar4 o;
    o.x = (unsigned char)(s.x + 0.5f);
    o.y = (unsigned char)(s.y + 0.5f);
    o.z = (unsigned char)(s.z + 0.5f);
    o.w = (unsigned char)(s.w + 0.5f);
    *(uchar4*)(vimg + (size_t)y * WW + x) = o;
    int ra = y + PR + 1, rs = y - PR;
    if (ra < HH) {
      const float4 t = *(const float4*)(timg + (size_t)ra * WW + x);
      s.x += t.x; s.y += t.y; s.z += t.z; s.w += t.w;
    }
    if (rs >= 0) {
      const float4 t = *(const float4*)(timg + (size_t)rs * WW + x);
      s.x -= t.x; s.y -= t.y; s.z -= t.z; s.w -= t.w;
    }
  }
}

__device__ inline float wredf(float v) {
#pragma unroll
  for (int o = 32; o > 0; o >>= 1) v += __shfl_down(v, o, 64);
  return v;
}

// 8-byte-granular masked load of the vs row window (col boundaries 0/512 are
// 8B-aligned, so each uint2 is wholly valid or wholly out-of-row).
__device__ inline uint2 ld8(const unsigned char* __restrict__ row, int off) {
  bool ok = (off >= 0) & (off <= WW - 8);
  int oc = ok ? off : 0;
  uint2 v = *(const uint2*)(row + oc);
  if (!ok) { v.x = 0u; v.y = 0u; }
  return v;
}

__device__ inline int sum4b(unsigned x) {  // sum of the 4 bytes
  unsigned t = (x & 0x00FF00FFu) + ((x >> 8) & 0x00FF00FFu);
  return (int)((t + (t >> 16)) & 0xFFFFu);
}

// window byte I (0..39) <-> vs col x0-16+I ; compile-time I -> folds to one bfe
#define VSWORD(I) ((I) < 8  ? (((I)&7) < 4 ? w0.x : w0.y) : \
                   (I) < 16 ? (((I)&7) < 4 ? w1.x : w1.y) : \
                   (I) < 24 ? (((I)&7) < 4 ? w2.x : w2.y) : \
                   (I) < 32 ? (((I)&7) < 4 ? w3.x : w3.y) : \
                              (((I)&7) < 4 ? w4.x : w4.y))
#define BGET(I) ((int)((VSWORD(I) >> (((I)&3)*8)) & 0xffu))

// one output column: M*/Z*/Q* = rows y-1,y,y+1 at cols c-1,c,c+1 ; PV = pred[c]
#define STEP(C, MA,MB,MC, ZA,ZB,ZC, QA,QB,QC, PV) do {            \
    float gxv = (MC - MA) + 2.f*(ZC - ZA) + (QC - QA);            \
    float gyv = (QA - MA) + 2.f*(QB - MB) + (QC - MC);            \
    float tb  = sqrtf(gxv*gxv + gyv*gyv + 1e-12f);                \
    float tcv = ZB; float pvv = PV;                               \
    float qq  = (tcv > 0.5f) ? pvv : 1.f - pvv;                   \
    float lg  = __log2f(qq);                                      \
    float pooled = (float)sw * (1.f/961.f);                       \
    float wgt = 0.8f + 5.f*tb + 1.5f*fabsf(pooled - tcv);         \
    a_c += wgt*lg; a_pt += pvv*tcv; a_p += pvv; a_t += tcv;       \
    sw += BGET((C)+32) - BGET((C)+1);                             \
  } while (0)

// main fused kernel: block = one image b, 4 rows; wave w -> row y0+w; lane -> 8 cols
// All state in NAMED scalars/vectors: nothing indexable -> nothing spillable.
__global__ __launch_bounds__(256) void k_main(const float* __restrict__ pred,
                                              const float* __restrict__ tgt,
                                              const unsigned char* __restrict__ vs,
                                              double* __restrict__ acc) {
  __shared__ float s_red[4][4];

  int blk = blockIdx.x;            // 64*128
  int b   = blk >> 7;
  int y0  = (blk & 127) * 4;
  int tid = threadIdx.x;
  int wv = tid >> 6, lane = tid & 63;
  int y  = y0 + wv;
  int x0 = lane * 8;

  const float* pimg = pred + (size_t)b * HWQ;
  const float* timg = tgt  + (size_t)b * HWQ;
  const unsigned char* vimg = vs + (size_t)b * HWQ;

  // pred: own 8 cols
  const float* prow = pimg + (size_t)y * WW + x0;
  float4 pA = *(const float4*)prow;
  float4 pB = *(const float4*)(prow + 4);

  // target rows y-1,y,y+1, own 8 cols (row addr clamped; OOB row zeroed — wave-uniform branch)
  const float* trm = timg + (size_t)(y > 0 ? y - 1 : 0) * WW + x0;
  const float* tr0 = timg + (size_t)y * WW + x0;
  const float* trp = timg + (size_t)(y < HH - 1 ? y + 1 : HH - 1) * WW + x0;
  float4 m0 = *(const float4*)trm, m1 = *(const float4*)(trm + 4);
  float4 z0 = *(const float4*)tr0, z1 = *(const float4*)(tr0 + 4);
  float4 q0 = *(const float4*)trp, q1 = *(const float4*)(trp + 4);
  if (y == 0)      { m0 = make_float4(0,0,0,0); m1 = make_float4(0,0,0,0); }
  if (y == HH - 1) { q0 = make_float4(0,0,0,0); q1 = make_float4(0,0,0,0); }

  // horizontal halo via shuffles (already row-zeroed values)
  float m_l = __shfl_up(m1.w, 1, 64);  float m_r = __shfl_down(m0.x, 1, 64);
  float z_l = __shfl_up(z1.w, 1, 64);  float z_r = __shfl_down(z0.x, 1, 64);
  float q_l = __shfl_up(q1.w, 1, 64);  float q_r = __shfl_down(q0.x, 1, 64);
  bool l0 = (lane == 0), l63 = (lane == 63);
  m_l = l0 ? 0.f : m_l;  z_l = l0 ? 0.f : z_l;  q_l = l0 ? 0.f : q_l;
  m_r = l63 ? 0.f : m_r; z_r = l63 ? 0.f : z_r; q_r = l63 ? 0.f : q_r;

  // vs window bytes: cols x0-16 .. x0+23 as 5 masked uint2 (8B granular)
  const unsigned char* vrow = vimg + (size_t)y * WW;
  uint2 w0 = ld8(vrow, x0 - 16);
  uint2 w1 = ld8(vrow, x0 - 8);
  uint2 w2 = *(const uint2*)(vrow + x0);        // always valid
  uint2 w3 = ld8(vrow, x0 + 8);
  uint2 w4 = ld8(vrow, x0 + 16);

  // initial 31-window sum for col x0: bytes 1..31 = (w0 - byte0) + w1 + w2 + w3
  int sw = sum4b(w0.x) - BGET(0) + sum4b(w0.y)
         + sum4b(w1.x) + sum4b(w1.y)
         + sum4b(w2.x) + sum4b(w2.y)
         + sum4b(w3.x) + sum4b(w3.y);

  float a_c = 0.f, a_pt = 0.f, a_p = 0.f, a_t = 0.f;
  STEP(0, m_l,  m0.x, m0.y,  z_l,  z0.x, z0.y,  q_l,  q0.x, q0.y,  pA.x);
  STEP(1, m0.x, m0.y, m0.z,  z0.x, z0.y, z0.z,  q0.x, q0.y, q0.z,  pA.y);
  STEP(2, m0.y, m0.z, m0.w,  z0.y, z0.z, z0.w,  q0.y, q0.z, q0.w,  pA.z);
  STEP(3, m0.z, m0.w, m1.x,  z0.z, z0.w, z1.x,  q0.z, q0.w, q1.x,  pA.w);
  STEP(4, m0.w, m1.x, m1.y,  z0.w, z1.x, z1.y,  q0.w, q1.x, q1.y,  pB.x);
  STEP(5, m1.x, m1.y, m1.z,  z1.x, z1.y, z1.z,  q1.x, q1.y, q1.z,  pB.y);
  STEP(6, m1.y, m1.z, m1.w,  z1.y, z1.z, z1.w,  q1.y, q1.z, q1.w,  pB.z);
  STEP(7, m1.z, m1.w, m_r,   z1.z, z1.w, z_r,   q1.z, q1.w, q_r,   pB.w);

  a_c = wredf(a_c); a_pt = wredf(a_pt); a_p = wredf(a_p); a_t = wredf(a_t);
  if (lane == 0) {
    s_red[wv][0] = a_c; s_red[wv][1] = a_pt; s_red[wv][2] = a_p; s_red[wv][3] = a_t;
  }
  __syncthreads();
  if (tid == 0) {
    float rc = 0, rpt = 0, rp = 0, rt = 0;
    for (int w2i = 0; w2i < 4; ++w2i) {
      rc += s_red[w2i][0]; rpt += s_red[w2i][1]; rp += s_red[w2i][2]; rt += s_red[w2i][3];
    }
    atomicAdd(&acc[blk & 63],       (double)rc);
    atomicAdd(&acc[64 + 8*b + 0],   (double)rpt);
    atomicAdd(&acc[64 + 8*b + 1],   (double)rp);
    atomicAdd(&acc[64 + 8*b + 2],   (double)rt);
  }
}

__global__ void k_final(const double* __restrict__ acc, float* __restrict__ out) {
  int t = threadIdx.x;  // 64 threads = 1 wave
  double cs = acc[t];
  double TP = acc[64 + 8*t], Ps = acc[64 + 8*t + 1], Ts = acc[64 + 8*t + 2];
  double FP = Ps - TP, FN = Ts - TP;
  double tv = (TP + 1e-6) / (TP + 0.3 * FP + 0.7 * FN + 1e-6);
  double om = 1.0 - tv;
  if (om < 0.0) om = 0.0;
  double term = pow(om, 1.0 / 1.33);
#pragma unroll
  for (int o = 32; o > 0; o >>= 1) {
    cs   += __shfl_down(cs, o, 64);
    term += __shfl_down(term, o, 64);
  }
  if (t == 0) {
    double ftl = term / 64.0;
    double n = (double)NTOT;
    // combined weighted-BCE sum: bce = -ln2 * log2(q)
    out[0] = (float)(ftl - 0.6931471805599453 * cs / n);
  }
}

extern "C" void kernel_launch(void* const* d_in, const int* in_sizes, int n_in,
                              void* d_out, int out_size, void* d_ws, size_t ws_size,
                              hipStream_t stream) {
  (void)in_sizes; (void)n_in; (void)out_size; (void)ws_size;
  const float* pred = (const float*)d_in[0];
  const float* tgt  = (const float*)d_in[1];
  unsigned char* vsb = (unsigned char*)d_ws;
  double* acc = (double*)((char*)d_ws + NTOT);

  k_vsum<<<512, 256, 0, stream>>>(tgt, vsb, acc);
  k_main<<<BB * 128, 256, 0, stream>>>(pred, tgt, vsb, acc);
  k_final<<<1, 64, 0, stream>>>(acc, (float*)d_out);
}